// Round 2
// baseline (507.897 us; speedup 1.0000x reference)
//
#include <hip/hip_runtime.h>
#include <hip/hip_cooperative_groups.h>
#include <math.h>

namespace cg = cooperative_groups;

// Problem constants (B=16, S=2048, H=1024)
#define BATCH 16
#define SEQ   2048
#define HID   1024

// ---------------------------------------------------------------------------
// Fully-fused cooperative kernel. grid = 1024 blocks x 256 threads
// (= 4 blocks/CU, 16 waves/CU -- safely co-resident for cooperative launch).
//
// P1: partial[chunk][j] = sum_{h in chunk(8)} v[h]*W[h,1024+j]   (blocks 0..127)
// P2: w2[j] = sum_chunk partial[chunk][j]                         (blocks 0..3)
// P3: scores[row] = enc[row,:] . w2  -- 8 rows per wave, 4096 waves
// P4: per-batch softmax                                           (blocks 0..15)
//
// grid.sync() between phases provides device-scope visibility (XCD-safe).
// hidden & attn_b are provably unused: their contribution is constant per
// batch row and cancels in softmax (verified: absmax 2.4e-7).
// ---------------------------------------------------------------------------
__global__ __launch_bounds__(256, 4) void fused_all_kernel(
    const float* __restrict__ attn_w,
    const float* __restrict__ v,
    const float* __restrict__ enc,
    float* __restrict__ ws,
    float* __restrict__ out)
{
    cg::grid_group grid = cg::this_grid();
    const int tid = threadIdx.x;
    const int bid = blockIdx.x;

    float* w2      = ws;                    // [1024]
    float* partial = ws + HID;              // [128][1024]
    float* scores  = ws + HID + 128 * HID;  // [16][2048]

    __shared__ float red[256];

    // ---- P1: partial mat-vec over the encoder half of attn_w --------------
    if (bid < 128) {
        const int h0 = bid * 8;
        float4 acc = make_float4(0.f, 0.f, 0.f, 0.f);
#pragma unroll
        for (int r = 0; r < 8; ++r) {
            const int h = h0 + r;
            const float vh = v[h];
            const float4 a =
                ((const float4*)(attn_w + (size_t)h * (2 * HID) + HID))[tid];
            acc.x += vh * a.x;
            acc.y += vh * a.y;
            acc.z += vh * a.z;
            acc.w += vh * a.w;
        }
        ((float4*)(partial + (size_t)bid * HID))[tid] = acc;
    }
    grid.sync();

    // ---- P2: reduce 128 partials -> w2 ------------------------------------
    if (bid < 4) {
        const int j = bid * 256 + tid;
        float a = 0.f;
#pragma unroll 8
        for (int y = 0; y < 128; ++y)
            a += partial[(size_t)y * HID + j];
        w2[j] = a;
    }
    grid.sync();

    // ---- P3: scores = enc . w2  (dominant phase, 134 MB stream) -----------
    {
        const int wave = (bid * 256 + tid) >> 6;  // 0..4095
        const int lane = tid & 63;

        float4 w[4];
#pragma unroll
        for (int c = 0; c < 4; ++c)
            w[c] = ((const float4*)w2)[c * 64 + lane];

#pragma unroll
        for (int i = 0; i < 8; ++i) {
            const int row = wave * 8 + i;  // 0..32767
            const float4* rp = (const float4*)(enc + (size_t)row * HID);
            float acc = 0.f;
#pragma unroll
            for (int c = 0; c < 4; ++c) {
                const float4 e = rp[c * 64 + lane];
                acc += e.x * w[c].x + e.y * w[c].y + e.z * w[c].z + e.w * w[c].w;
            }
#pragma unroll
            for (int off = 32; off > 0; off >>= 1)
                acc += __shfl_down(acc, off, 64);
            if (lane == 0)
                scores[row] = acc;
        }
    }
    grid.sync();

    // ---- P4: per-batch softmax --------------------------------------------
    if (bid < BATCH) {
        const float* s = scores + (size_t)bid * SEQ;

        float local[8];
        float m = -INFINITY;
#pragma unroll
        for (int i = 0; i < 8; ++i) {
            local[i] = s[tid + i * 256];
            m = fmaxf(m, local[i]);
        }
        red[tid] = m;
        __syncthreads();
        for (int st = 128; st > 0; st >>= 1) {
            if (tid < st) red[tid] = fmaxf(red[tid], red[tid + st]);
            __syncthreads();
        }
        m = red[0];
        __syncthreads();

        float e[8];
        float sum = 0.f;
#pragma unroll
        for (int i = 0; i < 8; ++i) {
            e[i] = __expf(local[i] - m);
            sum += e[i];
        }
        red[tid] = sum;
        __syncthreads();
        for (int st = 128; st > 0; st >>= 1) {
            if (tid < st) red[tid] += red[tid + st];
            __syncthreads();
        }
        const float inv = 1.f / red[0];
#pragma unroll
        for (int i = 0; i < 8; ++i)
            out[(size_t)bid * SEQ + tid + i * 256] = e[i] * inv;
    }
}

// ---------------------------------------------------------------------------
// Fallback path (the harness-verified 4-dispatch pipeline) in case the
// cooperative launch is rejected on this runtime.
// ---------------------------------------------------------------------------
__global__ __launch_bounds__(256) void we_partial_kernel(
    const float* __restrict__ attn_w,
    const float* __restrict__ v,
    float* __restrict__ partial)
{
    const int tid   = threadIdx.x;
    const int chunk = blockIdx.x;
    const int h0    = chunk * 8;

    float4 acc = make_float4(0.f, 0.f, 0.f, 0.f);
#pragma unroll
    for (int r = 0; r < 8; ++r) {
        const int h = h0 + r;
        const float vh = v[h];
        const float4 a =
            ((const float4*)(attn_w + (size_t)h * (2 * HID) + HID))[tid];
        acc.x += vh * a.x;
        acc.y += vh * a.y;
        acc.z += vh * a.z;
        acc.w += vh * a.w;
    }
    ((float4*)(partial + (size_t)chunk * HID))[tid] = acc;
}

__global__ __launch_bounds__(256) void we_reduce_kernel(
    const float* __restrict__ partial,
    float* __restrict__ w2)
{
    const int j = blockIdx.x * 256 + threadIdx.x;
    float acc = 0.f;
#pragma unroll 8
    for (int y = 0; y < 128; ++y)
        acc += partial[(size_t)y * HID + j];
    w2[j] = acc;
}

__global__ __launch_bounds__(256) void scores_kernel(
    const float* __restrict__ enc,
    const float* __restrict__ w2,
    float* __restrict__ scores)
{
    const int wave = (int)((blockIdx.x * 256 + threadIdx.x) >> 6);
    const int lane = threadIdx.x & 63;

    float4 w[4];
#pragma unroll
    for (int c = 0; c < 4; ++c)
        w[c] = ((const float4*)w2)[c * 64 + lane];

#pragma unroll
    for (int i = 0; i < 4; ++i) {
        const int row = wave * 4 + i;
        const float4* rp = (const float4*)(enc + (size_t)row * HID);
        float acc = 0.f;
#pragma unroll
        for (int c = 0; c < 4; ++c) {
            const float4 e = rp[c * 64 + lane];
            acc += e.x * w[c].x + e.y * w[c].y + e.z * w[c].z + e.w * w[c].w;
        }
#pragma unroll
        for (int off = 32; off > 0; off >>= 1)
            acc += __shfl_down(acc, off, 64);
        if (lane == 0)
            scores[row] = acc;
    }
}

__global__ __launch_bounds__(256) void softmax_kernel(
    const float* __restrict__ scores,
    float* __restrict__ out)
{
    const int b   = blockIdx.x;
    const int tid = threadIdx.x;
    const float* s = scores + (size_t)b * SEQ;

    __shared__ float red[256];

    float local[8];
    float m = -INFINITY;
#pragma unroll
    for (int i = 0; i < 8; ++i) {
        local[i] = s[tid + i * 256];
        m = fmaxf(m, local[i]);
    }
    red[tid] = m;
    __syncthreads();
    for (int st = 128; st > 0; st >>= 1) {
        if (tid < st) red[tid] = fmaxf(red[tid], red[tid + st]);
        __syncthreads();
    }
    m = red[0];
    __syncthreads();

    float e[8];
    float sum = 0.f;
#pragma unroll
    for (int i = 0; i < 8; ++i) {
        e[i] = __expf(local[i] - m);
        sum += e[i];
    }
    red[tid] = sum;
    __syncthreads();
    for (int st = 128; st > 0; st >>= 1) {
        if (tid < st) red[tid] += red[tid + st];
        __syncthreads();
    }
    const float inv = 1.f / red[0];
#pragma unroll
    for (int i = 0; i < 8; ++i)
        out[(size_t)b * SEQ + tid + i * 256] = e[i] * inv;
}

// ---------------------------------------------------------------------------
// Launch.  Inputs (fp32): hidden[16384], encoder_outputs[33554432],
// attn_w[2097152], attn_b[1024], v[1024].  Output: fp32 [16*2048].
//
// ws layout (floats): [0,1024)=w2 | [1024,132096)=partials | [132096,164864)=scores
// ---------------------------------------------------------------------------
extern "C" void kernel_launch(void* const* d_in, const int* in_sizes, int n_in,
                              void* d_out, int out_size, void* d_ws, size_t ws_size,
                              hipStream_t stream)
{
    const float* enc    = (const float*)d_in[1];
    const float* attn_w = (const float*)d_in[2];
    const float* v      = (const float*)d_in[4];

    float* ws     = (float*)d_ws;
    float* outp   = (float*)d_out;

    void* args[] = {(void*)&attn_w, (void*)&v, (void*)&enc,
                    (void*)&ws, (void*)&outp};
    hipError_t err = hipLaunchCooperativeKernel(
        (const void*)fused_all_kernel, dim3(1024), dim3(256), args, 0, stream);

    if (err != hipSuccess) {
        // Fallback: verified 4-dispatch pipeline.
        float* w2      = ws;
        float* partial = ws + HID;
        float* scores  = ws + HID + 128 * HID;
        we_partial_kernel<<<128,  256, 0, stream>>>(attn_w, v, partial);
        we_reduce_kernel <<<4,    256, 0, stream>>>(partial, w2);
        scores_kernel    <<<2048, 256, 0, stream>>>(enc, w2, scores);
        softmax_kernel   <<<BATCH, 256, 0, stream>>>(scores, outp);
    }
}

// Round 3
// 214.855 us; speedup vs baseline: 2.3639x; 2.3639x over previous
//
#include <hip/hip_runtime.h>
#include <math.h>

// Problem constants (B=16, S=2048, H=1024)
#define BATCH 16
#define SEQ   2048
#define HID   1024

// ---------------------------------------------------------------------------
// Kernel A: partial mat-vec  partial[chunk][j] = sum_{h in chunk} v[h]*W[h,1024+j]
// attn_w is [H, 2H] row-major; we only need columns [H, 2H) (the encoder half;
// the hidden half feeds a per-row constant that cancels in softmax).
// grid = 128 blocks (8 rows each), block = 256 threads * float4 = 1024 cols.
// ---------------------------------------------------------------------------
__global__ __launch_bounds__(256) void we_partial_kernel(
    const float* __restrict__ attn_w,
    const float* __restrict__ v,
    float* __restrict__ partial)
{
    const int tid   = threadIdx.x;     // 0..255
    const int chunk = blockIdx.x;      // 0..127
    const int h0    = chunk * 8;

    float4 acc = make_float4(0.f, 0.f, 0.f, 0.f);
#pragma unroll
    for (int r = 0; r < 8; ++r) {
        const int h = h0 + r;
        const float vh = v[h];
        const float4 a =
            ((const float4*)(attn_w + (size_t)h * (2 * HID) + HID))[tid];
        acc.x += vh * a.x;
        acc.y += vh * a.y;
        acc.z += vh * a.z;
        acc.w += vh * a.w;
    }
    ((float4*)(partial + (size_t)chunk * HID))[tid] = acc;
}

// ---------------------------------------------------------------------------
// Kernel B: w2[j] = sum_{chunk<128} partial[chunk][j].  grid=4, block=256.
// 512 KB, L2-hot.
// ---------------------------------------------------------------------------
__global__ __launch_bounds__(256) void we_reduce_kernel(
    const float* __restrict__ partial,
    float* __restrict__ w2)
{
    const int j = blockIdx.x * 256 + threadIdx.x;  // 0..1023
    float acc = 0.f;
#pragma unroll 8
    for (int y = 0; y < 128; ++y)
        acc += partial[(size_t)y * HID + j];
    w2[j] = acc;
}

// ---------------------------------------------------------------------------
// Kernel C (dominant): scores[row] = enc[row,:] . w2   for row in [0, B*S).
// One wave per 4 rows; lane l covers elements {c*256 + l*4 .. +3 | c<4}.
// w2 fragment (16 floats) preloaded into VGPRs, amortized over 4 rows.
// v2: accumulate all 4 rows first (16 independent float4 loads in flight),
// then a batched __shfl_xor butterfly (6 rounds x 4 independent chains,
// ~6x DS latency on the critical path instead of 24x), then lanes 0..3
// store 4 consecutive scores (coalesced).
// grid = 2048 blocks * 256 thr = 8192 waves = 32 waves/CU (full occupancy).
// 134 MB encoder read -> HBM/L3-bound.
// ---------------------------------------------------------------------------
__global__ __launch_bounds__(256) void scores_kernel(
    const float* __restrict__ enc,
    const float* __restrict__ w2,
    float* __restrict__ scores)
{
    const int wave = (int)((blockIdx.x * 256 + threadIdx.x) >> 6); // 0..8191
    const int lane = threadIdx.x & 63;

    float4 w[4];
#pragma unroll
    for (int c = 0; c < 4; ++c)
        w[c] = ((const float4*)w2)[c * 64 + lane];

    float a0 = 0.f, a1 = 0.f, a2 = 0.f, a3 = 0.f;
    const float4* rp0 = (const float4*)(enc + (size_t)(wave * 4 + 0) * HID);
    const float4* rp1 = (const float4*)(enc + (size_t)(wave * 4 + 1) * HID);
    const float4* rp2 = (const float4*)(enc + (size_t)(wave * 4 + 2) * HID);
    const float4* rp3 = (const float4*)(enc + (size_t)(wave * 4 + 3) * HID);

#pragma unroll
    for (int c = 0; c < 4; ++c) {
        const float4 e0 = rp0[c * 64 + lane];
        const float4 e1 = rp1[c * 64 + lane];
        const float4 e2 = rp2[c * 64 + lane];
        const float4 e3 = rp3[c * 64 + lane];
        a0 += e0.x * w[c].x + e0.y * w[c].y + e0.z * w[c].z + e0.w * w[c].w;
        a1 += e1.x * w[c].x + e1.y * w[c].y + e1.z * w[c].z + e1.w * w[c].w;
        a2 += e2.x * w[c].x + e2.y * w[c].y + e2.z * w[c].z + e2.w * w[c].w;
        a3 += e3.x * w[c].x + e3.y * w[c].y + e3.z * w[c].z + e3.w * w[c].w;
    }

    // Batched wave64 butterfly: 6 rounds, 4 independent chains per round.
#pragma unroll
    for (int off = 32; off > 0; off >>= 1) {
        a0 += __shfl_xor(a0, off, 64);
        a1 += __shfl_xor(a1, off, 64);
        a2 += __shfl_xor(a2, off, 64);
        a3 += __shfl_xor(a3, off, 64);
    }

    if (lane < 4) {
        const float val = (lane == 0) ? a0 : (lane == 1) ? a1
                        : (lane == 2) ? a2 : a3;
        scores[wave * 4 + lane] = val;   // 4 consecutive floats, coalesced
    }
}

// ---------------------------------------------------------------------------
// Kernel D: row softmax over [BATCH, SEQ].  One block per batch row.
// ---------------------------------------------------------------------------
__global__ __launch_bounds__(256) void softmax_kernel(
    const float* __restrict__ scores,
    float* __restrict__ out)
{
    const int b   = blockIdx.x;
    const int tid = threadIdx.x;
    const float* s = scores + (size_t)b * SEQ;

    __shared__ float red[256];

    float local[8];
    float m = -INFINITY;
#pragma unroll
    for (int i = 0; i < 8; ++i) {
        local[i] = s[tid + i * 256];
        m = fmaxf(m, local[i]);
    }
    red[tid] = m;
    __syncthreads();
    for (int st = 128; st > 0; st >>= 1) {
        if (tid < st) red[tid] = fmaxf(red[tid], red[tid + st]);
        __syncthreads();
    }
    m = red[0];
    __syncthreads();

    float e[8];
    float sum = 0.f;
#pragma unroll
    for (int i = 0; i < 8; ++i) {
        e[i] = __expf(local[i] - m);
        sum += e[i];
    }
    red[tid] = sum;
    __syncthreads();
    for (int st = 128; st > 0; st >>= 1) {
        if (tid < st) red[tid] += red[tid + st];
        __syncthreads();
    }
    const float inv = 1.f / red[0];
#pragma unroll
    for (int i = 0; i < 8; ++i)
        out[(size_t)b * SEQ + tid + i * 256] = e[i] * inv;
}

// ---------------------------------------------------------------------------
// Launch.  Inputs (fp32): hidden[16384], encoder_outputs[33554432],
// attn_w[2097152], attn_b[1024], v[1024].  Output: fp32 [16*2048].
// hidden & attn_b are provably unused (per-row constants cancel in softmax).
//
// ws layout (floats): [0,1024)=w2 | [1024,132096)=partials | [132096,164864)=scores
// total 644 KB.
// ---------------------------------------------------------------------------
extern "C" void kernel_launch(void* const* d_in, const int* in_sizes, int n_in,
                              void* d_out, int out_size, void* d_ws, size_t ws_size,
                              hipStream_t stream)
{
    const float* enc    = (const float*)d_in[1];
    const float* attn_w = (const float*)d_in[2];
    const float* v      = (const float*)d_in[4];

    float* ws      = (float*)d_ws;
    float* w2      = ws;
    float* partial = ws + HID;
    float* scores  = ws + HID + 128 * HID;

    we_partial_kernel<<<128, 256, 0, stream>>>(attn_w, v, partial);
    we_reduce_kernel <<<4,   256, 0, stream>>>(partial, w2);
    scores_kernel    <<<2048, 256, 0, stream>>>(enc, w2, scores);
    softmax_kernel   <<<BATCH, 256, 0, stream>>>(scores, (float*)d_out);
}